// Round 7
// baseline (141.656 us; speedup 1.0000x reference)
//
#include <hip/hip_runtime.h>
#include <math.h>

#define Bn 4
#define Nn 512
#define Dn 64
#define Hn 8
#define TR 32          // rows per tile-block
#define NT (Nn / TR)   // 16 tiles per (b,q)
#define PS 36          // ehat row stride (words); heads -> banks 4h%32, distinct
#define PART 80        // partial floats per block: 64 PV + 8 expsum + 8 gsum

typedef float f32x4 __attribute__((ext_vector_type(4)));

// ---------------- Kernel 1: QKV projection -------------------------------
__global__ __launch_bounds__(64) void qkv_kernel(
    const float* __restrict__ nin, const float* __restrict__ Wq,
    const float* __restrict__ Wk, const float* __restrict__ Wv,
    float* __restrict__ Qw, float* __restrict__ Kw, float* __restrict__ Vw)
{
    const int row = blockIdx.x;   // 0 .. B*N-1
    const int d = threadIdx.x;    // 0 .. 63
    __shared__ float nrow[Dn];
    nrow[d] = nin[row * Dn + d];
    __syncthreads();
    float aq = 0.f, ak = 0.f, av = 0.f;
#pragma unroll
    for (int k = 0; k < Dn; ++k) {
        const float nv = nrow[k];
        aq = fmaf(nv, Wq[k * Dn + d], aq);
        ak = fmaf(nv, Wk[k * Dn + d], ak);
        av = fmaf(nv, Wv[k * Dn + d], av);
    }
    Qw[row * Dn + d] = aq;
    Kw[row * Dn + d] = ak;
    Vw[row * Dn + d] = av;
}

// ---------------- Kernel 2: streaming tile kernel -------------------------
// One block per (b,q,tile): 32 m-rows, 16.6KB LDS -> 8 blocks/CU = 32 waves
// (100% occupancy). Lane = (row, head-half): 64 lanes = 32 rows x 2 heads,
// wave w owns head-pair {2w,2w+1}. Coalesced 8KB e-read -> XOR-swizzled LDS
// -> eb/gg/A/ehat -> e_out per-output-chunk, nt full-line stores -> PV/
// expsum/gsum partial. reduce_kernel folds partials into n_out.
__global__ __launch_bounds__(256, 8) void stream_kernel(
    const float* __restrict__ e,
    const float* __restrict__ Qw, const float* __restrict__ Kw,
    const float* __restrict__ Vw,
    const float* __restrict__ WeG, const float* __restrict__ WgG,
    const float* __restrict__ OeG,
    float* __restrict__ eout, float* __restrict__ part)
{
    const int bid  = blockIdx.x;        // bq*NT + tile
    const int bq   = bid >> 4;          // NT = 16
    const int tile = bid & 15;
    const int b    = bq >> 9;           // N = 512
    const int m0   = tile * TR;
    const int t    = threadIdx.x;       // 0..255
    const int w    = t >> 6;            // wave 0..3 = head-pair {2w,2w+1}
    const int l    = t & 63;
    const int row  = l & 31;            // row within tile
    const int hh   = l >> 5;            // head-half 0/1
    const int h    = 2 * w + hh;        // this lane's head for eb/gg/A

    __shared__ float e_tile[TR * Dn];               // 8192 B, swizzled groups
    __shared__ float ehat_s[Hn * PS];               // 1152 B
    __shared__ __align__(16) float we_s[Hn][Dn];    // 2048 B
    __shared__ __align__(16) float wg_s[Hn][Dn];    // 2048 B
    __shared__ __align__(16) float oe_s[Hn][Dn];    // 2048 B
    __shared__ float accb[4][Dn];                   // 1024 B
    __shared__ float ssb[Hn], gsb[Hn];              // 64 B

    // 1) e-tile loads first (HBM latency): 8KB contiguous, 2 float4/thread
    float4 st[2];
    {
        const float4* ep = (const float4*)(e + ((size_t)bq * Nn + m0) * Dn);
#pragma unroll
        for (int j = 0; j < 2; ++j) st[j] = ep[j * 256 + t];
    }

    // 2) A = clip(Q.K*scale) for this lane's (row, head) (K/Q L2-hot)
    float a0;
    {
        const float4* kp = (const float4*)(Kw + ((size_t)b * Nn + m0 + row) * Dn + h * 8);
        const float4 k0 = kp[0], k1 = kp[1];
        const float4* qp = (const float4*)(Qw + (size_t)bq * Dn + h * 8);
        const float4 q0 = qp[0], q1 = qp[1];
        const float qscale = 0.35355339059327373f;  // 1/sqrt(8)
        a0 = k0.x*q0.x + k0.y*q0.y + k0.z*q0.z + k0.w*q0.w
           + k1.x*q1.x + k1.y*q1.y + k1.z*q1.z + k1.w*q1.w;
        a0 = fminf(fmaxf(a0 * qscale, -5.f), 5.f);
    }

    // 3) weights (L2-hot). We/Wg (D,H) -> [h][d]; Oe (H,D) copy.
    for (int i = t; i < Dn * Hn; i += 256) {
        const int d = i >> 3, hw = i & 7;
        we_s[hw][d] = WeG[i];
        wg_s[hw][d] = WgG[i];
        ((float*)oe_s)[i] = OeG[i];
    }

    // 4) staged e -> swizzled LDS: chunk (r,g) -> slot (r, g^(r&15))
#pragma unroll
    for (int j = 0; j < 2; ++j) {
        const int c = j * 256 + t, r = c >> 4, g = c & 15;
        *(float4*)&e_tile[r * Dn + ((g ^ (r & 15)) << 2)] = st[j];
    }
    __syncthreads();

    // 5) eb/gg dots for (row, h): e from swizzled LDS, weights broadcast
    float eb0 = 0.f, gg0 = 0.f;
    {
        const float4* weh = (const float4*)we_s[h];
        const float4* wgh = (const float4*)wg_s[h];
#pragma unroll
        for (int d4 = 0; d4 < 16; ++d4) {
            const float4 e4 = *(const float4*)&e_tile[row * Dn + ((d4 ^ (row & 15)) << 2)];
            const float4 A0 = weh[d4];
            const float4 G0 = wgh[d4];
            eb0 = fmaf(e4.x, A0.x, fmaf(e4.y, A0.y, fmaf(e4.z, A0.z, fmaf(e4.w, A0.w, eb0))));
            gg0 = fmaf(e4.x, G0.x, fmaf(e4.y, G0.y, fmaf(e4.z, G0.z, fmaf(e4.w, G0.w, gg0))));
        }
    }

    // 6) ehat -> LDS; per-head exp-sum and sigmoid-sum via 32-lane shuffles
    {
        const float eh0 = a0 + eb0;
        ehat_s[h * PS + row] = eh0;
        float p0 = __expf(eh0);
        float g0 = 1.f / (1.f + __expf(-gg0));
#pragma unroll
        for (int off = 16; off > 0; off >>= 1) {   // sums within 32-lane half
            p0 += __shfl_xor(p0, off, 64);
            g0 += __shfl_xor(g0, off, 64);
        }
        if (row == 0) { ssb[h] = p0; gsb[h] = g0; }
    }
    __syncthreads();   // ehat/ssb/gsb ready; eb-phase done with e_tile

    // 7) e_out: thread owns chunk c -> row r, colgroup cc; ehat via LDS
    //    broadcast; nt full-line coalesced stores (8KB contiguous/block)
    {
        float4* eo = (float4*)(eout + ((size_t)bq * Nn + m0) * Dn);
#pragma unroll
        for (int j = 0; j < 2; ++j) {
            const int c = j * 256 + t, r = c >> 4, cc = c & 15;
            f32x4 o = {0.f, 0.f, 0.f, 0.f};
#pragma unroll
            for (int ho = 0; ho < Hn; ++ho) {
                const float ehv = ehat_s[ho * PS + r];
                const float4 w4 = *(const float4*)&oe_s[ho][cc * 4];
                o.x = fmaf(ehv, w4.x, o.x);
                o.y = fmaf(ehv, w4.y, o.y);
                o.z = fmaf(ehv, w4.z, o.z);
                o.w = fmaf(ehv, w4.w, o.w);
            }
            __builtin_nontemporal_store(o, (f32x4*)eo + c);
        }
    }

    // 8) PV partials: wave w covers rows w*8..w*8+7; p = exp(ehat)
    {
        const int hc = l >> 3;      // head for output col l
        float acc = 0.f;
        const float* vrow = Vw + ((size_t)b * Nn + m0 + w * 8) * Dn;
#pragma unroll
        for (int i = 0; i < 8; ++i) {
            const float p = __expf(ehat_s[hc * PS + w * 8 + i]);
            acc = fmaf(p, vrow[i * Dn + l], acc);
        }
        accb[w][l] = acc;
    }
    __syncthreads();

    // 9) fold 4 waves, emit 80-float partial
    if (w == 0) {
        const float O = accb[0][l] + accb[1][l] + accb[2][l] + accb[3][l];
        float* pb = part + (size_t)bid * PART;
        pb[l] = O;
        if (l < 8) { pb[64 + l] = ssb[l]; pb[72 + l] = gsb[l]; }
    }
}

// ---------------- Kernel 3: fold partials -> n_out ------------------------
__global__ __launch_bounds__(64) void reduce_kernel(
    const float* __restrict__ part, const float* __restrict__ WoG,
    float* __restrict__ nout)
{
    const int bq = blockIdx.x;
    const int l  = threadIdx.x;
    const int h  = l >> 3;
    const float* pb = part + (size_t)bq * NT * PART;
    float O = 0.f, S = 0.f, G = 0.f;
#pragma unroll
    for (int tl = 0; tl < NT; ++tl) {
        O += pb[tl * PART + l];
        S += pb[tl * PART + 64 + h];
        G += pb[tl * PART + 72 + h];
    }
    __shared__ float vo_s[Dn];
    vo_s[l] = (O / S) * log1pf(G);
    __syncthreads();
    float a = 0.f;
#pragma unroll
    for (int k = 0; k < Dn; ++k)
        a = fmaf(vo_s[k], WoG[k * Dn + l], a);
    nout[(size_t)bq * Dn + l] = a;
}

// ---------------- Host launcher -------------------------------------------
extern "C" void kernel_launch(void* const* d_in, const int* in_sizes, int n_in,
                              void* d_out, int out_size, void* d_ws, size_t ws_size,
                              hipStream_t stream)
{
    (void)in_sizes; (void)n_in; (void)out_size; (void)ws_size;
    const float* nin = (const float*)d_in[0];
    const float* e   = (const float*)d_in[1];
    const float* Wq  = (const float*)d_in[2];
    const float* Wk  = (const float*)d_in[3];
    const float* Wv  = (const float*)d_in[4];
    const float* Wo  = (const float*)d_in[5];
    const float* Wg  = (const float*)d_in[6];
    const float* We  = (const float*)d_in[7];
    const float* Oe  = (const float*)d_in[8];

    float* Qw   = (float*)d_ws;               // B*N*D floats
    float* Kw   = Qw + Bn * Nn * Dn;
    float* Vw   = Kw + Bn * Nn * Dn;
    float* part = Vw + Bn * Nn * Dn;          // B*N*NT*PART floats (10.5 MB)

    float* nout = (float*)d_out;              // B*N*D floats
    float* eout = nout + Bn * Nn * Dn;        // B*N*N*D floats

    qkv_kernel<<<Bn * Nn, 64, 0, stream>>>(nin, Wq, Wk, Wv, Qw, Kw, Vw);
    stream_kernel<<<Bn * Nn * NT, 256, 0, stream>>>(e, Qw, Kw, Vw, We, Wg, Oe,
                                                    eout, part);
    reduce_kernel<<<Bn * Nn, 64, 0, stream>>>(part, Wo, nout);
}